// Round 20
// baseline (90.831 us; speedup 1.0000x reference)
//
#include <hip/hip_runtime.h>
#include <hip/hip_bf16.h>
#include <math.h>

// Single-head causal attention with fused QKV projection.
// B=16, T=4096, D_MODEL=512, HEAD_DIM=64. fp32 in/out, bf16 MFMA internally.
//
// R20 = R18 (best passing: 512-thr blocks, 8 waves = 4 q-tiles x 2 KV
// parities, 4-tile rounds, double-buffered 64KB KV, two barriers/round,
// vmcnt(4) counted staging) + ones-MFMA lsum from R19 (rowsum on the idle
// matrix pipe; lacc[0] is the full 32-key sum -> VALU tree and final shfl
// deleted). R19's 4-slot rotation is dead: 4 rounds x 32KB = 128KB > LDS.
// In-register P core unchanged. proj = R13 version.

#define NB 16
#define NT 4096
#define DMODEL 512
#define HD 64
#define CEXP 0.18033688011112042f   // log2(e)/8

typedef unsigned short u16;
typedef unsigned int u32;
typedef __attribute__((ext_vector_type(2))) unsigned int u32x2;
typedef __attribute__((ext_vector_type(8))) short bf16x8;
typedef __attribute__((ext_vector_type(4))) float f32x4;
typedef __attribute__((ext_vector_type(16))) float f32x16;

__device__ __forceinline__ u16 bfu(float x) {
  __hip_bfloat16 h = __float2bfloat16(x);
  return *(u16*)&h;
}

__device__ __forceinline__ u32 cvtpk(float lo, float hi) {
  u32 r;
  asm("v_cvt_pk_bf16_f32 %0, %1, %2" : "=v"(r) : "v"(lo), "v"(hi));
  return r;
}

// v_permlane32_swap_b32: a'[i<32]=a[i], a'[i>=32]=b[i-32]; b'[i<32]=a[i+32].
__device__ __forceinline__ u32x2 lane_swap(u32 a, u32 b) {
  asm("v_permlane32_swap_b32 %0, %1" : "+v"(a), "+v"(b));
  u32x2 r; r[0] = a; r[1] = b; return r;
}

__device__ __forceinline__ void gload16(const void* g, void* l) {
  __builtin_amdgcn_global_load_lds(
      (const __attribute__((address_space(1))) void*)g,
      (__attribute__((address_space(3))) void*)l, 16, 0, 0);
}

#define MFMA32(a, b, c) __builtin_amdgcn_mfma_f32_16x16x32_bf16(a, b, c, 0, 0, 0)
#define WMFMA(a, b, c)  __builtin_amdgcn_mfma_f32_32x32x16_bf16(a, b, c, 0, 0, 0)
#define LD8(p) (*(const bf16x8*)(p))

// ---------------------------------------------------------------------------
// Kernel 1: Wt[n][k] = W_{n/64}[k][n%64] as bf16, n in [0,192), k in [0,512).
// ---------------------------------------------------------------------------
__global__ void prep_wt(const float* __restrict__ Wq, const float* __restrict__ Wk,
                        const float* __restrict__ Wv, u16* __restrict__ Wt) {
  int k0 = blockIdx.x * 16;
  int t = threadIdx.x;
#pragma unroll
  for (int i = 0; i < 12; ++i) {
    int idx = t + i * 256;      // [0, 3072)
    int n = idx % 192;
    int kk = idx / 192;         // [0, 16)
    const float* W = (n < 64) ? Wq : (n < 128) ? Wk : Wv;
    float w = W[(size_t)(k0 + kk) * 64 + (n & 63)];
    Wt[(size_t)n * 512 + k0 + kk] = bfu(w);
  }
}

// ---------------------------------------------------------------------------
// Kernel 2 (R13 version): q = (x@Wq)*CEXP row-major bf16 [B*T][64];
//   k tiled fragment-order: kt[b*128+tile][dt][h][l31][8] = K[key][d]
//   v tiled fragment-order: vt[b*128+tile][dh][kt][h][l31][8] = V[key][d]
// 512 threads (8 waves, 2x4), BM=128, BN=192, BK=32.
// Double-buffered As (one barrier/step), depth-3 x prefetch.
// ---------------------------------------------------------------------------
__global__ __launch_bounds__(512) void proj_qkv(const float* __restrict__ x,
                                                const u16* __restrict__ Wt,
                                                u16* __restrict__ qo,
                                                u16* __restrict__ ko,
                                                u16* __restrict__ vo) {
  __shared__ u16 As[2][128][48];   // 32 k + 16 pad, double-buffered
  int t = threadIdx.x;
  int m0 = blockIdx.x * 128;
  int lane = t & 63, wid = t >> 6;
  int wr = wid >> 2, wc = wid & 3;
  int g = lane >> 4, li = lane & 15;
  f32x4 acc[4][3];
#pragma unroll
  for (int i = 0; i < 4; ++i)
#pragma unroll
    for (int j = 0; j < 3; ++j) acc[i][j] = (f32x4){0.f, 0.f, 0.f, 0.f};

  int row = t >> 2, quad = t & 3;
  const float* srcb = x + (size_t)(m0 + row) * DMODEL + quad * 8;

  float4 pa0[3], pa1[3];   // depth-3 prefetch slots (static idx in unroll)
#pragma unroll
  for (int s = 0; s < 3; ++s) {
    pa0[s] = *(const float4*)(srcb + s * 32);
    pa1[s] = *(const float4*)(srcb + s * 32 + 4);
  }

#pragma unroll
  for (int s = 0; s < 16; ++s) {
    float4 c0 = pa0[s % 3], c1 = pa1[s % 3];
    if (s + 3 < 16) {
      pa0[s % 3] = *(const float4*)(srcb + (s + 3) * 32);
      pa1[s % 3] = *(const float4*)(srcb + (s + 3) * 32 + 4);
    }
    union { u16 u[8]; bf16x8 v; } tmp;
    tmp.u[0] = bfu(c0.x); tmp.u[1] = bfu(c0.y);
    tmp.u[2] = bfu(c0.z); tmp.u[3] = bfu(c0.w);
    tmp.u[4] = bfu(c1.x); tmp.u[5] = bfu(c1.y);
    tmp.u[6] = bfu(c1.z); tmp.u[7] = bfu(c1.w);
    *(bf16x8*)&As[s & 1][row][quad * 8] = tmp.v;
    __syncthreads();   // write(s) visible; also fences write(s+2) vs read(s)

    int k0 = s * 32;
    bf16x8 a[4], bb[3];
#pragma unroll
    for (int mf = 0; mf < 4; ++mf)
      a[mf] = *(const bf16x8*)&As[s & 1][wr * 64 + mf * 16 + li][g * 8];
#pragma unroll
    for (int nf = 0; nf < 3; ++nf)
      bb[nf] = *(const bf16x8*)(Wt + (size_t)(wc * 48 + nf * 16 + li) * 512 + k0 + g * 8);
#pragma unroll
    for (int mf = 0; mf < 4; ++mf)
#pragma unroll
      for (int nf = 0; nf < 3; ++nf)
        acc[mf][nf] = MFMA32(a[mf], bb[nf], acc[mf][nf]);
  }

  // D layout: col = lane&15, row = 4*(lane>>4)+r
#pragma unroll
  for (int nf = 0; nf < 3; ++nf) {
    int n = wc * 48 + nf * 16 + li;
    if (n < 64) {            // Q: row-major, scale folded (in f32)
      int col = n;
#pragma unroll
      for (int mf = 0; mf < 4; ++mf)
#pragma unroll
        for (int r = 0; r < 4; ++r) {
          int m = m0 + wr * 64 + mf * 16 + 4 * g + r;
          qo[(size_t)m * HD + col] = bfu(acc[mf][nf][r] * CEXP);
        }
    } else if (n < 128) {    // K: tiled fragment order
      int col = n & 63;
      int dt = col >> 4, hh = (col >> 3) & 1, jj = col & 7;
      size_t fo = (size_t)(dt * 2 + hh) * 256 + jj;
#pragma unroll
      for (int mf = 0; mf < 4; ++mf)
#pragma unroll
        for (int r = 0; r < 4; ++r) {
          int m = m0 + wr * 64 + mf * 16 + 4 * g + r;
          ko[(size_t)(m >> 5) * 2048 + fo + (m & 31) * 8] = bfu(acc[mf][nf][r]);
        }
    } else {                 // V: tiled fragment order, ushort4 stores
      int d = n - 128;
      int dh = d >> 5, l31d = d & 31;
#pragma unroll
      for (int mf = 0; mf < 4; ++mf) {
        int mbase = m0 + wr * 64 + mf * 16 + 4 * g;   // 4-aligned
        int kk2 = mbase & 31;
        int kt2 = kk2 >> 4, hh = (kk2 >> 3) & 1;
        size_t off = (size_t)(mbase >> 5) * 2048 +
                     (size_t)((dh * 2 + kt2) * 2 + hh) * 256 + l31d * 8 + (mbase & 7);
        ushort4 pk;
        pk.x = bfu(acc[mf][nf][0]);
        pk.y = bfu(acc[mf][nf][1]);
        pk.z = bfu(acc[mf][nf][2]);
        pk.w = bfu(acc[mf][nf][3]);
        *(ushort4*)(vo + off) = pk;
      }
    }
  }
}

// ---------------------------------------------------------------------------
// Kernel 3: causal flash attention (R18 pipeline + ones-MFMA lsum).
// 512 threads (8 waves = 4 q-tiles x 2 KV parities), 128 q-rows/block,
// LDS-shared KV double buffer (2x32KB), 4 tiles/barrier-round, vmcnt(4).
// Grid 512; CU pairing (b even, bp=31-i) with (b odd, bp=i).
// Wave w = qi*2+ki: q-tile rows bp*128+qi*32, KV tiles j == ki (mod 2),
// j <= diag = 4bp+qi. Staging: wave w loads the K-half (w&1==0) or V-half
// of tile w>>1 (4 gload16 -> vmcnt(4) exact). lsum via ones-MFMA (lacc[0]
// = full 32-key sum; no VALU tree, no shfl).
// ---------------------------------------------------------------------------
__global__ __launch_bounds__(512, 4) void attn_fwd20(const u16* __restrict__ qg,
                                                     const u16* __restrict__ kg,
                                                     const u16* __restrict__ vg,
                                                     float* __restrict__ out) {
  __shared__ __align__(16) char smem[65536];
  u16* KV = (u16*)smem;            // [2][16384]: (K0|V0|K1|V1|K2|V2|K3|V3)
  float* MrgF = (float*)smem;      // [8][64][17] during merge passes

  int tid = threadIdx.x;
  int lane = tid & 63, w = tid >> 6;
  int l31 = lane & 31, h = lane >> 5;
  int qi = w >> 1, ki = w & 1;

  // uniform pairing: i<32 -> (b=2xcd, bp=31-i); i>=32 -> (b=2xcd+1, bp=i-32)
  int f = blockIdx.x;
  int xcd = f & 7, i = f >> 3;     // i in [0,64)
  int b, bp;
  if (i < 32) { b = 2 * xcd;     bp = 31 - i; }
  else        { b = 2 * xcd + 1; bp = i - 32; }

  const int limb = 4 * bp + 3;     // last KV tile needed by the block
  const int diagw = 4 * bp + qi;   // q-tile qi's diagonal KV tile
  const int nr = bp + 1;           // rounds of 4 tiles
  const int q0w = bp * 128 + qi * 32;

  const u16* qb = qg + (size_t)b * NT * HD;
  const u16* kbs = kg + (size_t)b * NT * HD;   // tiled [128][2048]
  const u16* vbs = vg + (size_t)b * NT * HD;
  float* ob = out + (size_t)b * NT * HD;

  // Q fragments (B-operand): lane holds Q[q0w+l31][dt*16 + 8h + jj]
  bf16x8 qf[4];
#pragma unroll
  for (int dt = 0; dt < 4; ++dt)
    qf[dt] = LD8(qb + (size_t)(q0w + l31) * HD + dt * 16 + 8 * h);

  bf16x8 ones;
#pragma unroll
  for (int r = 0; r < 8; ++r) ones[r] = (short)0x3F80;

  f32x16 oacc0, oacc1, lacc;  // O^T halves + rowsum (lacc[0] = full sum)
#pragma unroll
  for (int r = 0; r < 16; ++r) { oacc0[r] = 0.f; oacc1[r] = 0.f; lacc[r] = 0.f; }

  auto STAGE = [&](u16* lb, int jr1) {   // stage round jr1's 4 tiles
    int t4 = w >> 1, part = w & 1;       // tile slot, K/V half
    int tg = min(4 * jr1 + t4, limb);
    const u16* gsrc = (part ? vbs : kbs) + (size_t)tg * 2048 + lane * 8;
    u16* dk = lb + t4 * 4096 + part * 2048 + lane * 8;
#pragma unroll
    for (int ii = 0; ii < 4; ++ii)
      gload16(gsrc + ii * 512, dk + ii * 512);
  };

  auto COMPUTE = [&](const u16* kp0, const u16* vp0, bool maskdiag) {
    bf16x8 kf[4], vf[4];
#pragma unroll
    for (int dt = 0; dt < 4; ++dt)
      kf[dt] = LD8(kp0 + dt * 512 + h * 256 + l31 * 8);
#pragma unroll
    for (int dv = 0; dv < 4; ++dv)   // dv = dh*2+kt
      vf[dv] = LD8(vp0 + dv * 512 + h * 256 + l31 * 8);

    f32x16 sv;
#pragma unroll
    for (int r = 0; r < 16; ++r) sv[r] = 0.f;
    sv = WMFMA(kf[0], qf[0], sv);
    sv = WMFMA(kf[1], qf[1], sv);
    sv = WMFMA(kf[2], qf[2], sv);
    sv = WMFMA(kf[3], qf[3], sv);

    if (maskdiag) {   // diagonal tile: causal mask (q0 cancels)
#pragma unroll
      for (int r = 0; r < 16; ++r) {
        int key = (r & 3) + 8 * (r >> 2) + 4 * h;
        if (key > l31) sv[r] = -1e30f;
      }
    }

    float p[16];
#pragma unroll
    for (int r = 0; r < 16; ++r) p[r] = __builtin_amdgcn_exp2f(sv[r]);
    u32 A0 = cvtpk(p[0], p[1]),   A1 = cvtpk(p[2], p[3]);
    u32 B0 = cvtpk(p[4], p[5]),   B1 = cvtpk(p[6], p[7]);
    u32 C0 = cvtpk(p[8], p[9]),   C1 = cvtpk(p[10], p[11]);
    u32 E0 = cvtpk(p[12], p[13]), E1 = cvtpk(p[14], p[15]);
    u32x2 s0 = lane_swap(A0, B0), s1 = lane_swap(A1, B1);
    u32x2 s2 = lane_swap(C0, E0), s3 = lane_swap(C1, E1);
    union { u32 d[4]; bf16x8 v; } f0u, f1u;   // B-frag: k = 8h+jj
    f0u.d[0] = s0[0]; f0u.d[1] = s1[0]; f0u.d[2] = s0[1]; f0u.d[3] = s1[1];
    f1u.d[0] = s2[0]; f1u.d[1] = s3[0]; f1u.d[2] = s2[1]; f1u.d[3] = s3[1];

    oacc0 = WMFMA(vf[0], f0u.v, oacc0);   // dh=0, kt=0
    oacc1 = WMFMA(vf[2], f0u.v, oacc1);   // dh=1, kt=0
    lacc  = WMFMA(ones,  f0u.v, lacc);    // rowsum, keys 0..15
    oacc0 = WMFMA(vf[1], f1u.v, oacc0);   // dh=0, kt=1
    oacc1 = WMFMA(vf[3], f1u.v, oacc1);   // dh=1, kt=1
    lacc  = WMFMA(ones,  f1u.v, lacc);    // rowsum, keys 16..31
  };

  // prologue: stage round 0's 4 tiles into buf 0
  STAGE(KV, 0);

  int cur = 0;
  for (int jr = 0; jr < nr; ++jr) {
    if (jr + 1 < nr) {   // stage next round's tiles (always 4 loads/wave)
      STAGE(KV + (cur ^ 1) * 16384, jr + 1);
      asm volatile("s_waitcnt vmcnt(4)" ::: "memory");   // this round landed
    } else {
      asm volatile("s_waitcnt vmcnt(0)" ::: "memory");
    }
    __builtin_amdgcn_sched_barrier(0);
    asm volatile("s_barrier" ::: "memory");

    const u16* kv0 = KV + cur * 16384;
    int j1 = 4 * jr + ki, j2 = 4 * jr + 2 + ki;   // local tiles ki, 2+ki
    __builtin_amdgcn_s_setprio(1);
    if (j1 <= diagw)
      COMPUTE(kv0 + ki * 4096, kv0 + ki * 4096 + 2048, j1 == diagw);
    if (j2 <= diagw)
      COMPUTE(kv0 + (2 + ki) * 4096, kv0 + (2 + ki) * 4096 + 2048, j2 == diagw);
    __builtin_amdgcn_s_setprio(0);

    asm volatile("s_barrier" ::: "memory");
    cur ^= 1;
  }

  // merge: 2 bounce passes (one d-half per pass), partner = other ki wave
  float lsum = lacc[0];   // full 32-key column sum (ones-A rows identical)
#pragma unroll
  for (int s = 0; s < 2; ++s) {
    __syncthreads();   // KV reads (s=0) / pass-0 reads (s=1) complete
    {
      float* mg = MrgF + ((size_t)w * 64 + lane) * 17;
      const f32x16& oS = s ? oacc1 : oacc0;
#pragma unroll
      for (int r = 0; r < 16; ++r) mg[r] = oS[r];
      mg[16] = lsum;
    }
    __syncthreads();
    const float* m0p = MrgF + ((size_t)(qi * 2) * 64) * 17;
    const float* m1p = MrgF + ((size_t)(qi * 2 + 1) * 64) * 17;
#pragma unroll
    for (int t2 = 0; t2 < 2; ++t2) {
      int ql = (lane >> 2) + 16 * t2;            // [0,32)
      float ls = m0p[(size_t)ql * 17 + 16] + m1p[(size_t)ql * 17 + 16];
      float inv = 1.0f / ls;
      f32x4 o4;
#pragma unroll
      for (int dd = 0; dd < 4; ++dd) {
        int rem = ki * 16 + (lane & 3) * 4 + dd; // [0,32) within d-half s
        int srch = (rem >> 2) & 1;
        int reg = (rem & 3) + ((rem >> 3) << 2);
        size_t ro = (size_t)(ql + 32 * srch) * 17 + reg;
        o4[dd] = (m0p[ro] + m1p[ro]) * inv;
      }
      int d0 = s * 32 + ki * 16 + (lane & 3) * 4;
      *(f32x4*)(ob + (size_t)(q0w + ql) * HD + d0) = o4;
    }
  }
}

// ---------------------------------------------------------------------------
extern "C" void kernel_launch(void* const* d_in, const int* in_sizes, int n_in,
                              void* d_out, int out_size, void* d_ws, size_t ws_size,
                              hipStream_t stream) {
  const float* x  = (const float*)d_in[0];
  const float* Wq = (const float*)d_in[1];
  const float* Wk = (const float*)d_in[2];
  const float* Wv = (const float*)d_in[3];
  float* out = (float*)d_out;

  // ws layout: Wt bf16 [192][512] | q [B*T][64] | k tiled | v tiled
  u16* Wt  = (u16*)d_ws;
  u16* qws = (u16*)((char*)d_ws + 192 * 512 * 2);
  u16* kws = qws + (size_t)NB * NT * HD;
  u16* vws = kws + (size_t)NB * NT * HD;

  prep_wt<<<32, 256, 0, stream>>>(Wq, Wk, Wv, Wt);
  proj_qkv<<<(NB * NT) / 128, 512, 0, stream>>>(x, Wt, qws, kws, vws);
  attn_fwd20<<<512, 512, 0, stream>>>(qws, kws, vws, out);
}

// Round 22
// 90.391 us; speedup vs baseline: 1.0049x; 1.0049x over previous
//
#include <hip/hip_runtime.h>
#include <hip/hip_bf16.h>
#include <math.h>

// Single-head causal attention with fused QKV projection.
// B=16, T=4096, D_MODEL=512, HEAD_DIM=64. fp32 in/out, bf16 MFMA internally.
//
// R22 = R18 restored verbatim (best measured: 90.45 us).
// proj: LDS-staged (R13), double-buffered As, one barrier/step, depth-3
// x prefetch. attn: 512-thr blocks (8 waves = 4 q-tiles x 2 KV parities,
// 128 q-rows), 64KB KV double buffer, 4-tile rounds, vmcnt(4) counted
// staging, 512 blocks = 16 waves/CU, 2-pass merge bounce. In-register P
// (swapped 32x32 QK^T, cvt_pk + permlane32_swap, max-free softmax, scale
// pre-folded into Q).

#define NB 16
#define NT 4096
#define DMODEL 512
#define HD 64
#define CEXP 0.18033688011112042f   // log2(e)/8

typedef unsigned short u16;
typedef unsigned int u32;
typedef __attribute__((ext_vector_type(2))) unsigned int u32x2;
typedef __attribute__((ext_vector_type(8))) short bf16x8;
typedef __attribute__((ext_vector_type(4))) float f32x4;
typedef __attribute__((ext_vector_type(16))) float f32x16;

__device__ __forceinline__ u16 bfu(float x) {
  __hip_bfloat16 h = __float2bfloat16(x);
  return *(u16*)&h;
}

__device__ __forceinline__ u32 cvtpk(float lo, float hi) {
  u32 r;
  asm("v_cvt_pk_bf16_f32 %0, %1, %2" : "=v"(r) : "v"(lo), "v"(hi));
  return r;
}

// v_permlane32_swap_b32: a'[i<32]=a[i], a'[i>=32]=b[i-32]; b'[i<32]=a[i+32].
__device__ __forceinline__ u32x2 lane_swap(u32 a, u32 b) {
  asm("v_permlane32_swap_b32 %0, %1" : "+v"(a), "+v"(b));
  u32x2 r; r[0] = a; r[1] = b; return r;
}

__device__ __forceinline__ void gload16(const void* g, void* l) {
  __builtin_amdgcn_global_load_lds(
      (const __attribute__((address_space(1))) void*)g,
      (__attribute__((address_space(3))) void*)l, 16, 0, 0);
}

#define MFMA32(a, b, c) __builtin_amdgcn_mfma_f32_16x16x32_bf16(a, b, c, 0, 0, 0)
#define WMFMA(a, b, c)  __builtin_amdgcn_mfma_f32_32x32x16_bf16(a, b, c, 0, 0, 0)
#define LD8(p) (*(const bf16x8*)(p))

// ---------------------------------------------------------------------------
// Kernel 1: Wt[n][k] = W_{n/64}[k][n%64] as bf16, n in [0,192), k in [0,512).
// ---------------------------------------------------------------------------
__global__ void prep_wt(const float* __restrict__ Wq, const float* __restrict__ Wk,
                        const float* __restrict__ Wv, u16* __restrict__ Wt) {
  int k0 = blockIdx.x * 16;
  int t = threadIdx.x;
#pragma unroll
  for (int i = 0; i < 12; ++i) {
    int idx = t + i * 256;      // [0, 3072)
    int n = idx % 192;
    int kk = idx / 192;         // [0, 16)
    const float* W = (n < 64) ? Wq : (n < 128) ? Wk : Wv;
    float w = W[(size_t)(k0 + kk) * 64 + (n & 63)];
    Wt[(size_t)n * 512 + k0 + kk] = bfu(w);
  }
}

// ---------------------------------------------------------------------------
// Kernel 2 (R13 version): q = (x@Wq)*CEXP row-major bf16 [B*T][64];
//   k tiled fragment-order: kt[b*128+tile][dt][h][l31][8] = K[key][d]
//   v tiled fragment-order: vt[b*128+tile][dh][kt][h][l31][8] = V[key][d]
// 512 threads (8 waves, 2x4), BM=128, BN=192, BK=32.
// Double-buffered As (one barrier/step), depth-3 x prefetch.
// ---------------------------------------------------------------------------
__global__ __launch_bounds__(512) void proj_qkv(const float* __restrict__ x,
                                                const u16* __restrict__ Wt,
                                                u16* __restrict__ qo,
                                                u16* __restrict__ ko,
                                                u16* __restrict__ vo) {
  __shared__ u16 As[2][128][48];   // 32 k + 16 pad, double-buffered
  int t = threadIdx.x;
  int m0 = blockIdx.x * 128;
  int lane = t & 63, wid = t >> 6;
  int wr = wid >> 2, wc = wid & 3;
  int g = lane >> 4, li = lane & 15;
  f32x4 acc[4][3];
#pragma unroll
  for (int i = 0; i < 4; ++i)
#pragma unroll
    for (int j = 0; j < 3; ++j) acc[i][j] = (f32x4){0.f, 0.f, 0.f, 0.f};

  int row = t >> 2, quad = t & 3;
  const float* srcb = x + (size_t)(m0 + row) * DMODEL + quad * 8;

  float4 pa0[3], pa1[3];   // depth-3 prefetch slots (static idx in unroll)
#pragma unroll
  for (int s = 0; s < 3; ++s) {
    pa0[s] = *(const float4*)(srcb + s * 32);
    pa1[s] = *(const float4*)(srcb + s * 32 + 4);
  }

#pragma unroll
  for (int s = 0; s < 16; ++s) {
    float4 c0 = pa0[s % 3], c1 = pa1[s % 3];
    if (s + 3 < 16) {
      pa0[s % 3] = *(const float4*)(srcb + (s + 3) * 32);
      pa1[s % 3] = *(const float4*)(srcb + (s + 3) * 32 + 4);
    }
    union { u16 u[8]; bf16x8 v; } tmp;
    tmp.u[0] = bfu(c0.x); tmp.u[1] = bfu(c0.y);
    tmp.u[2] = bfu(c0.z); tmp.u[3] = bfu(c0.w);
    tmp.u[4] = bfu(c1.x); tmp.u[5] = bfu(c1.y);
    tmp.u[6] = bfu(c1.z); tmp.u[7] = bfu(c1.w);
    *(bf16x8*)&As[s & 1][row][quad * 8] = tmp.v;
    __syncthreads();   // write(s) visible; also fences write(s+2) vs read(s)

    int k0 = s * 32;
    bf16x8 a[4], bb[3];
#pragma unroll
    for (int mf = 0; mf < 4; ++mf)
      a[mf] = *(const bf16x8*)&As[s & 1][wr * 64 + mf * 16 + li][g * 8];
#pragma unroll
    for (int nf = 0; nf < 3; ++nf)
      bb[nf] = *(const bf16x8*)(Wt + (size_t)(wc * 48 + nf * 16 + li) * 512 + k0 + g * 8);
#pragma unroll
    for (int mf = 0; mf < 4; ++mf)
#pragma unroll
      for (int nf = 0; nf < 3; ++nf)
        acc[mf][nf] = MFMA32(a[mf], bb[nf], acc[mf][nf]);
  }

  // D layout: col = lane&15, row = 4*(lane>>4)+r
#pragma unroll
  for (int nf = 0; nf < 3; ++nf) {
    int n = wc * 48 + nf * 16 + li;
    if (n < 64) {            // Q: row-major, scale folded (in f32)
      int col = n;
#pragma unroll
      for (int mf = 0; mf < 4; ++mf)
#pragma unroll
        for (int r = 0; r < 4; ++r) {
          int m = m0 + wr * 64 + mf * 16 + 4 * g + r;
          qo[(size_t)m * HD + col] = bfu(acc[mf][nf][r] * CEXP);
        }
    } else if (n < 128) {    // K: tiled fragment order
      int col = n & 63;
      int dt = col >> 4, hh = (col >> 3) & 1, jj = col & 7;
      size_t fo = (size_t)(dt * 2 + hh) * 256 + jj;
#pragma unroll
      for (int mf = 0; mf < 4; ++mf)
#pragma unroll
        for (int r = 0; r < 4; ++r) {
          int m = m0 + wr * 64 + mf * 16 + 4 * g + r;
          ko[(size_t)(m >> 5) * 2048 + fo + (m & 31) * 8] = bfu(acc[mf][nf][r]);
        }
    } else {                 // V: tiled fragment order, ushort4 stores
      int d = n - 128;
      int dh = d >> 5, l31d = d & 31;
#pragma unroll
      for (int mf = 0; mf < 4; ++mf) {
        int mbase = m0 + wr * 64 + mf * 16 + 4 * g;   // 4-aligned
        int kk2 = mbase & 31;
        int kt2 = kk2 >> 4, hh = (kk2 >> 3) & 1;
        size_t off = (size_t)(mbase >> 5) * 2048 +
                     (size_t)((dh * 2 + kt2) * 2 + hh) * 256 + l31d * 8 + (mbase & 7);
        ushort4 pk;
        pk.x = bfu(acc[mf][nf][0]);
        pk.y = bfu(acc[mf][nf][1]);
        pk.z = bfu(acc[mf][nf][2]);
        pk.w = bfu(acc[mf][nf][3]);
        *(ushort4*)(vo + off) = pk;
      }
    }
  }
}

// ---------------------------------------------------------------------------
// Kernel 3: causal flash attention, 512 threads (8 waves = 4 q-tiles x 2
// KV parities), 128 q-rows/block, LDS-shared KV, 4 tiles/barrier-round.
// Grid 512. Block (b, bp): CU pairing (b even, bp=31-i) with (b odd, bp=i).
// Wave w = qi*2+ki: q-tile rows bp*128+qi*32, KV tiles j == ki (mod 2),
// j <= diag = 4bp+qi; 2 visits/round. Staging: wave w loads the K-half
// (w&1==0) or V-half of tile w>>1 (4 gload16 -> vmcnt(4) exact).
// ---------------------------------------------------------------------------
__global__ __launch_bounds__(512, 4) void attn_fwd22(const u16* __restrict__ qg,
                                                     const u16* __restrict__ kg,
                                                     const u16* __restrict__ vg,
                                                     float* __restrict__ out) {
  __shared__ __align__(16) char smem[65536];
  u16* KV = (u16*)smem;            // [2][16384]: (K0|V0|K1|V1|K2|V2|K3|V3)
  float* MrgF = (float*)smem;      // [8][64][17] during merge passes

  int tid = threadIdx.x;
  int lane = tid & 63, w = tid >> 6;
  int l31 = lane & 31, h = lane >> 5;
  int qi = w >> 1, ki = w & 1;

  // uniform pairing: i<32 -> (b=2xcd, bp=31-i); i>=32 -> (b=2xcd+1, bp=i-32)
  int f = blockIdx.x;
  int xcd = f & 7, i = f >> 3;     // i in [0,64)
  int b, bp;
  if (i < 32) { b = 2 * xcd;     bp = 31 - i; }
  else        { b = 2 * xcd + 1; bp = i - 32; }

  const int limb = 4 * bp + 3;     // last KV tile needed by the block
  const int diagw = 4 * bp + qi;   // q-tile qi's diagonal KV tile
  const int nr = bp + 1;           // rounds of 4 tiles
  const int q0w = bp * 128 + qi * 32;

  const u16* qb = qg + (size_t)b * NT * HD;
  const u16* kbs = kg + (size_t)b * NT * HD;   // tiled [128][2048]
  const u16* vbs = vg + (size_t)b * NT * HD;
  float* ob = out + (size_t)b * NT * HD;

  // Q fragments (B-operand): lane holds Q[q0w+l31][dt*16 + 8h + jj]
  bf16x8 qf[4];
#pragma unroll
  for (int dt = 0; dt < 4; ++dt)
    qf[dt] = LD8(qb + (size_t)(q0w + l31) * HD + dt * 16 + 8 * h);

  f32x16 oacc0, oacc1;   // O^T[d = dh*32 + (r&3)+8*(r>>2)+4h][q = q0w+l31]
#pragma unroll
  for (int r = 0; r < 16; ++r) { oacc0[r] = 0.f; oacc1[r] = 0.f; }
  float lsum = 0.f;

  auto STAGE = [&](u16* lb, int jr1) {   // stage round jr1's 4 tiles
    int t4 = w >> 1, part = w & 1;       // tile slot, K/V half
    int tg = min(4 * jr1 + t4, limb);
    const u16* gsrc = (part ? vbs : kbs) + (size_t)tg * 2048 + lane * 8;
    u16* dk = lb + t4 * 4096 + part * 2048 + lane * 8;
#pragma unroll
    for (int ii = 0; ii < 4; ++ii)
      gload16(gsrc + ii * 512, dk + ii * 512);
  };

  auto COMPUTE = [&](const u16* kp0, const u16* vp0, bool maskdiag) {
    bf16x8 kf[4], vf[4];
#pragma unroll
    for (int dt = 0; dt < 4; ++dt)
      kf[dt] = LD8(kp0 + dt * 512 + h * 256 + l31 * 8);
#pragma unroll
    for (int dv = 0; dv < 4; ++dv)   // dv = dh*2+kt
      vf[dv] = LD8(vp0 + dv * 512 + h * 256 + l31 * 8);

    f32x16 sv;
#pragma unroll
    for (int r = 0; r < 16; ++r) sv[r] = 0.f;
    sv = WMFMA(kf[0], qf[0], sv);
    sv = WMFMA(kf[1], qf[1], sv);
    sv = WMFMA(kf[2], qf[2], sv);
    sv = WMFMA(kf[3], qf[3], sv);

    if (maskdiag) {   // diagonal tile: causal mask (q0 cancels)
#pragma unroll
      for (int r = 0; r < 16; ++r) {
        int key = (r & 3) + 8 * (r >> 2) + 4 * h;
        if (key > l31) sv[r] = -1e30f;
      }
    }

    float p[16];
#pragma unroll
    for (int r = 0; r < 16; ++r) p[r] = __builtin_amdgcn_exp2f(sv[r]);
    lsum += (((p[0] + p[1]) + (p[2] + p[3])) + ((p[4] + p[5]) + (p[6] + p[7]))) +
            (((p[8] + p[9]) + (p[10] + p[11])) + ((p[12] + p[13]) + (p[14] + p[15])));
    u32 A0 = cvtpk(p[0], p[1]),   A1 = cvtpk(p[2], p[3]);
    u32 B0 = cvtpk(p[4], p[5]),   B1 = cvtpk(p[6], p[7]);
    u32 C0 = cvtpk(p[8], p[9]),   C1 = cvtpk(p[10], p[11]);
    u32 E0 = cvtpk(p[12], p[13]), E1 = cvtpk(p[14], p[15]);
    u32x2 s0 = lane_swap(A0, B0), s1 = lane_swap(A1, B1);
    u32x2 s2 = lane_swap(C0, E0), s3 = lane_swap(C1, E1);
    union { u32 d[4]; bf16x8 v; } f0u, f1u;   // B-frag: k = 8h+jj
    f0u.d[0] = s0[0]; f0u.d[1] = s1[0]; f0u.d[2] = s0[1]; f0u.d[3] = s1[1];
    f1u.d[0] = s2[0]; f1u.d[1] = s3[0]; f1u.d[2] = s2[1]; f1u.d[3] = s3[1];

    oacc0 = WMFMA(vf[0], f0u.v, oacc0);   // dh=0, kt=0
    oacc1 = WMFMA(vf[2], f0u.v, oacc1);   // dh=1, kt=0
    oacc0 = WMFMA(vf[1], f1u.v, oacc0);   // dh=0, kt=1
    oacc1 = WMFMA(vf[3], f1u.v, oacc1);   // dh=1, kt=1
  };

  // prologue: stage round 0's 4 tiles into buf 0
  STAGE(KV, 0);

  int cur = 0;
  for (int jr = 0; jr < nr; ++jr) {
    if (jr + 1 < nr) {   // stage next round's tiles (always 4 loads/wave)
      STAGE(KV + (cur ^ 1) * 16384, jr + 1);
      asm volatile("s_waitcnt vmcnt(4)" ::: "memory");   // this round landed
    } else {
      asm volatile("s_waitcnt vmcnt(0)" ::: "memory");
    }
    __builtin_amdgcn_sched_barrier(0);
    asm volatile("s_barrier" ::: "memory");

    const u16* kv0 = KV + cur * 16384;
    int j1 = 4 * jr + ki, j2 = 4 * jr + 2 + ki;   // local tiles ki, 2+ki
    __builtin_amdgcn_s_setprio(1);
    if (j1 <= diagw)
      COMPUTE(kv0 + ki * 4096, kv0 + ki * 4096 + 2048, j1 == diagw);
    if (j2 <= diagw)
      COMPUTE(kv0 + (2 + ki) * 4096, kv0 + (2 + ki) * 4096 + 2048, j2 == diagw);
    __builtin_amdgcn_s_setprio(0);

    asm volatile("s_barrier" ::: "memory");
    cur ^= 1;
  }

  // merge: 2 bounce passes (one d-half per pass), partner = other ki wave
  lsum += __shfl_xor(lsum, 32);
#pragma unroll
  for (int s = 0; s < 2; ++s) {
    __syncthreads();   // KV reads (s=0) / pass-0 reads (s=1) complete
    {
      float* mg = MrgF + ((size_t)w * 64 + lane) * 17;
      const f32x16& oS = s ? oacc1 : oacc0;
#pragma unroll
      for (int r = 0; r < 16; ++r) mg[r] = oS[r];
      mg[16] = lsum;
    }
    __syncthreads();
    const float* m0p = MrgF + ((size_t)(qi * 2) * 64) * 17;
    const float* m1p = MrgF + ((size_t)(qi * 2 + 1) * 64) * 17;
#pragma unroll
    for (int t2 = 0; t2 < 2; ++t2) {
      int ql = (lane >> 2) + 16 * t2;            // [0,32)
      float ls = m0p[(size_t)ql * 17 + 16] + m1p[(size_t)ql * 17 + 16];
      float inv = 1.0f / ls;
      f32x4 o4;
#pragma unroll
      for (int dd = 0; dd < 4; ++dd) {
        int rem = ki * 16 + (lane & 3) * 4 + dd; // [0,32) within d-half s
        int srch = (rem >> 2) & 1;
        int reg = (rem & 3) + ((rem >> 3) << 2);
        size_t ro = (size_t)(ql + 32 * srch) * 17 + reg;
        o4[dd] = (m0p[ro] + m1p[ro]) * inv;
      }
      int d0 = s * 32 + ki * 16 + (lane & 3) * 4;
      *(f32x4*)(ob + (size_t)(q0w + ql) * HD + d0) = o4;
    }
  }
}

// ---------------------------------------------------------------------------
extern "C" void kernel_launch(void* const* d_in, const int* in_sizes, int n_in,
                              void* d_out, int out_size, void* d_ws, size_t ws_size,
                              hipStream_t stream) {
  const float* x  = (const float*)d_in[0];
  const float* Wq = (const float*)d_in[1];
  const float* Wk = (const float*)d_in[2];
  const float* Wv = (const float*)d_in[3];
  float* out = (float*)d_out;

  // ws layout: Wt bf16 [192][512] | q [B*T][64] | k tiled | v tiled
  u16* Wt  = (u16*)d_ws;
  u16* qws = (u16*)((char*)d_ws + 192 * 512 * 2);
  u16* kws = qws + (size_t)NB * NT * HD;
  u16* vws = kws + (size_t)NB * NT * HD;

  prep_wt<<<32, 256, 0, stream>>>(Wq, Wk, Wv, Wt);
  proj_qkv<<<(NB * NT) / 128, 512, 0, stream>>>(x, Wt, qws, kws, vws);
  attn_fwd22<<<512, 512, 0, stream>>>(qws, kws, vws, out);
}